// Round 1
// baseline (228.382 us; speedup 1.0000x reference)
//
#include <hip/hip_runtime.h>

// CustomPuzzleLoss: loss1 = mean|p - t|, loss2 = 0.1 * dup_count/B over 5x5
// grids (rows+cols, exact float equality, "seen earlier in row" semantics),
// +1000 if any p outside [0.5, 5.5]. Output: single float scalar.

#define BLOCK 256
#define GRIDS_PER_BLOCK 256
#define ELEMS_PER_BLOCK (GRIDS_PER_BLOCK * 25)  // 6400 floats per block
#define NWAVES (BLOCK / 64)

__global__ __launch_bounds__(BLOCK) void puzzle_main(
    const float* __restrict__ preds, const int* __restrict__ tgts,
    long long n_total,
    float* __restrict__ blk_sum, int* __restrict__ blk_dup,
    int* __restrict__ blk_oob)
{
    __shared__ float lds[ELEMS_PER_BLOCK];   // 25600 B -> 6 blocks/CU on LDS
    __shared__ float s_sum[NWAVES];
    __shared__ int   s_dup[NWAVES];
    __shared__ int   s_oob[NWAVES];

    const int tid = threadIdx.x;
    const long long base = (long long)blockIdx.x * ELEMS_PER_BLOCK;
    long long rem = n_total - base;
    const int nelem = (int)(rem < ELEMS_PER_BLOCK ? rem : ELEMS_PER_BLOCK);

    const float4* __restrict__ p4 = (const float4*)(preds + base);
    const int4*   __restrict__ t4 = (const int4*)(tgts + base);

    // --- pass 1: coalesced vectorized load; loss1 + oob + LDS staging ---
    float lsum = 0.0f;
    int   loob = 0;
    const int nvec = nelem >> 2;
    for (int i = tid; i < nvec; i += BLOCK) {
        const float4 p = p4[i];
        const int4   t = t4[i];
        lsum += fabsf(p.x - (float)t.x);
        lsum += fabsf(p.y - (float)t.y);
        lsum += fabsf(p.z - (float)t.z);
        lsum += fabsf(p.w - (float)t.w);
        loob |= (int)((p.x < 0.5f) | (p.x > 5.5f));
        loob |= (int)((p.y < 0.5f) | (p.y > 5.5f));
        loob |= (int)((p.z < 0.5f) | (p.z > 5.5f));
        loob |= (int)((p.w < 0.5f) | (p.w > 5.5f));
        reinterpret_cast<float4*>(lds)[i] = p;
    }
    // scalar tail (only possible in the final block if n % 4 != 0)
    for (int i = (nvec << 2) + tid; i < nelem; i += BLOCK) {
        const float p = preds[base + i];
        const int   t = tgts[base + i];
        lsum += fabsf(p - (float)t);
        loob |= (int)((p < 0.5f) | (p > 5.5f));
        lds[i] = p;
    }
    __syncthreads();

    // --- pass 2: one thread per 5x5 grid; duplicate counting from LDS ---
    // LDS read addr = tid*25 + j : 25 is odd -> 2-way bank aliasing (free).
    int ldup = 0;
    const int ngrids = nelem / 25;
    if (tid < ngrids) {
        const float* g = &lds[tid * 25];
        // rows: element j is a dup if equal to any earlier k<j in its row
        #pragma unroll
        for (int r = 0; r < 5; ++r) {
            const float a = g[r*5+0], b = g[r*5+1], c = g[r*5+2],
                        d = g[r*5+3], e = g[r*5+4];
            ldup += (int)(b == a);
            ldup += (int)((c == a) | (c == b));
            ldup += (int)((d == a) | (d == b) | (d == c));
            ldup += (int)((e == a) | (e == b) | (e == c) | (e == d));
        }
        // cols: same on the transposed grid
        #pragma unroll
        for (int q = 0; q < 5; ++q) {
            const float a = g[q +  0], b = g[q +  5], c = g[q + 10],
                        d = g[q + 15], e = g[q + 20];
            ldup += (int)(b == a);
            ldup += (int)((c == a) | (c == b));
            ldup += (int)((d == a) | (d == b) | (d == c));
            ldup += (int)((e == a) | (e == b) | (e == c) | (e == d));
        }
    }

    // --- block reduction: wave shuffle then cross-wave via LDS ---
    #pragma unroll
    for (int off = 32; off > 0; off >>= 1) {
        lsum += __shfl_down(lsum, off, 64);
        ldup += __shfl_down(ldup, off, 64);
        loob |= __shfl_down(loob, off, 64);
    }
    const int wave = tid >> 6;
    if ((tid & 63) == 0) { s_sum[wave] = lsum; s_dup[wave] = ldup; s_oob[wave] = loob; }
    __syncthreads();
    if (tid == 0) {
        float bs = 0.0f; int bd = 0, bo = 0;
        #pragma unroll
        for (int w = 0; w < NWAVES; ++w) { bs += s_sum[w]; bd += s_dup[w]; bo |= s_oob[w]; }
        blk_sum[blockIdx.x] = bs;
        blk_dup[blockIdx.x] = bd;
        blk_oob[blockIdx.x] = bo;
    }
}

__global__ __launch_bounds__(BLOCK) void puzzle_final(
    const float* __restrict__ blk_sum, const int* __restrict__ blk_dup,
    const int* __restrict__ blk_oob, int nblocks,
    long long n_total, long long batch, float* __restrict__ out)
{
    __shared__ double s_sum[NWAVES];
    __shared__ int    s_dup[NWAVES];
    __shared__ int    s_oob[NWAVES];

    double lsum = 0.0;
    int ldup = 0, loob = 0;
    for (int i = threadIdx.x; i < nblocks; i += BLOCK) {
        lsum += (double)blk_sum[i];
        ldup += blk_dup[i];
        loob |= blk_oob[i];
    }
    #pragma unroll
    for (int off = 32; off > 0; off >>= 1) {
        lsum += __shfl_down(lsum, off, 64);
        ldup += __shfl_down(ldup, off, 64);
        loob |= __shfl_down(loob, off, 64);
    }
    const int wave = threadIdx.x >> 6;
    if ((threadIdx.x & 63) == 0) { s_sum[wave] = lsum; s_dup[wave] = ldup; s_oob[wave] = loob; }
    __syncthreads();
    if (threadIdx.x == 0) {
        double bs = 0.0; int bd = 0, bo = 0;
        #pragma unroll
        for (int w = 0; w < NWAVES; ++w) { bs += s_sum[w]; bd += s_dup[w]; bo |= s_oob[w]; }
        const float loss1 = (float)(bs / (double)n_total);
        const float loss2 = (float)((double)bd * 0.1 / (double)batch);
        out[0] = loss1 + loss2 + (bo ? 1000.0f : 0.0f);
    }
}

extern "C" void kernel_launch(void* const* d_in, const int* in_sizes, int n_in,
                              void* d_out, int out_size, void* d_ws, size_t ws_size,
                              hipStream_t stream) {
    const float* preds = (const float*)d_in[0];
    const int*   tgts  = (const int*)d_in[1];
    float* out = (float*)d_out;

    const long long n = (long long)in_sizes[0];
    const long long batch = n / 25;
    const int nblocks = (int)((n + ELEMS_PER_BLOCK - 1) / ELEMS_PER_BLOCK);

    // workspace layout: [float sums | int dups | int oobs], each nblocks long
    float* blk_sum = (float*)d_ws;
    int*   blk_dup = (int*)(blk_sum + nblocks);
    int*   blk_oob = (int*)(blk_dup + nblocks);

    puzzle_main<<<nblocks, BLOCK, 0, stream>>>(preds, tgts, n,
                                               blk_sum, blk_dup, blk_oob);
    puzzle_final<<<1, BLOCK, 0, stream>>>(blk_sum, blk_dup, blk_oob,
                                          nblocks, n, batch, out);
}

// Round 2
// 224.538 us; speedup vs baseline: 1.0171x; 1.0171x over previous
//
#include <hip/hip_runtime.h>

// CustomPuzzleLoss: loss1 = mean|p - t|, loss2 = 0.1 * dup_count/B over 5x5
// grids (rows+cols, exact float equality, "seen earlier" semantics),
// +1000 if any p outside [0.5, 5.5]. Output: single float scalar.
//
// R2: BLOCK=320 so pass-1 trip count is an exact constant (5 float4 + 5 int4
// per thread) -> full unroll, 10 loads in flight per thread (was ~2 at
// VGPR=40, 1.25 TB/s latency-bound).

#define BLOCK 320                         // 5 waves
#define GRIDS_PER_BLOCK 256
#define ELEMS_PER_BLOCK (GRIDS_PER_BLOCK * 25)   // 6400 floats
#define VEC_ITERS (ELEMS_PER_BLOCK / 4 / BLOCK)  // 1600/320 = 5 exactly
#define NWAVES (BLOCK / 64)

__device__ __forceinline__ int grid_dups(const float* __restrict__ g) {
    int ldup = 0;
    // rows: element j is a dup if equal to any earlier k<j in its row
    #pragma unroll
    for (int r = 0; r < 5; ++r) {
        const float a = g[r*5+0], b = g[r*5+1], c = g[r*5+2],
                    d = g[r*5+3], e = g[r*5+4];
        ldup += (int)(b == a);
        ldup += (int)((c == a) | (c == b));
        ldup += (int)((d == a) | (d == b) | (d == c));
        ldup += (int)((e == a) | (e == b) | (e == c) | (e == d));
    }
    // cols: same on the transposed grid
    #pragma unroll
    for (int q = 0; q < 5; ++q) {
        const float a = g[q +  0], b = g[q +  5], c = g[q + 10],
                    d = g[q + 15], e = g[q + 20];
        ldup += (int)(b == a);
        ldup += (int)((c == a) | (c == b));
        ldup += (int)((d == a) | (d == b) | (d == c));
        ldup += (int)((e == a) | (e == b) | (e == c) | (e == d));
    }
    return ldup;
}

__global__ __launch_bounds__(BLOCK) void puzzle_main(
    const float* __restrict__ preds, const int* __restrict__ tgts,
    long long n_total,
    float* __restrict__ blk_sum, int* __restrict__ blk_dup,
    int* __restrict__ blk_oob)
{
    __shared__ float lds[ELEMS_PER_BLOCK];   // 25600 B -> 6 blocks/CU on LDS
    __shared__ float s_sum[NWAVES];
    __shared__ int   s_dup[NWAVES];
    __shared__ int   s_oob[NWAVES];

    const int tid = threadIdx.x;
    const long long base = (long long)blockIdx.x * ELEMS_PER_BLOCK;
    const long long rem = n_total - base;
    const int nelem = (int)(rem < ELEMS_PER_BLOCK ? rem : ELEMS_PER_BLOCK);

    const float4* __restrict__ p4 = (const float4*)(preds + base);
    const int4*   __restrict__ t4 = (const int4*)(tgts + base);
    float4* __restrict__ lds4 = reinterpret_cast<float4*>(lds);

    float lsum = 0.0f;
    int   loob = 0;

    if (nelem == ELEMS_PER_BLOCK) {
        // --- fast path: constant trip count, full unroll, max MLP ---
        float4 p[VEC_ITERS];
        int4   t[VEC_ITERS];
        #pragma unroll
        for (int k = 0; k < VEC_ITERS; ++k) p[k] = p4[tid + k * BLOCK];
        #pragma unroll
        for (int k = 0; k < VEC_ITERS; ++k) t[k] = t4[tid + k * BLOCK];
        #pragma unroll
        for (int k = 0; k < VEC_ITERS; ++k) {
            lds4[tid + k * BLOCK] = p[k];
            lsum += fabsf(p[k].x - (float)t[k].x);
            lsum += fabsf(p[k].y - (float)t[k].y);
            lsum += fabsf(p[k].z - (float)t[k].z);
            lsum += fabsf(p[k].w - (float)t[k].w);
            loob |= (int)((p[k].x < 0.5f) | (p[k].x > 5.5f));
            loob |= (int)((p[k].y < 0.5f) | (p[k].y > 5.5f));
            loob |= (int)((p[k].z < 0.5f) | (p[k].z > 5.5f));
            loob |= (int)((p[k].w < 0.5f) | (p[k].w > 5.5f));
        }
    } else {
        // --- tail block fallback ---
        const int nvec = nelem >> 2;
        for (int i = tid; i < nvec; i += BLOCK) {
            const float4 p = p4[i];
            const int4   t = t4[i];
            lsum += fabsf(p.x - (float)t.x) + fabsf(p.y - (float)t.y) +
                    fabsf(p.z - (float)t.z) + fabsf(p.w - (float)t.w);
            loob |= (int)((p.x < 0.5f) | (p.x > 5.5f));
            loob |= (int)((p.y < 0.5f) | (p.y > 5.5f));
            loob |= (int)((p.z < 0.5f) | (p.z > 5.5f));
            loob |= (int)((p.w < 0.5f) | (p.w > 5.5f));
            lds4[i] = p;
        }
        for (int i = (nvec << 2) + tid; i < nelem; i += BLOCK) {
            const float p = preds[base + i];
            const int   t = tgts[base + i];
            lsum += fabsf(p - (float)t);
            loob |= (int)((p < 0.5f) | (p > 5.5f));
            lds[i] = p;
        }
    }
    __syncthreads();

    // --- pass 2: one thread per 5x5 grid; LDS addr stride 25 (odd) ->
    // 2-way bank aliasing only (free on gfx950) ---
    int ldup = 0;
    const int ngrids = nelem / 25;
    if (tid < ngrids) ldup = grid_dups(&lds[tid * 25]);

    // --- block reduction: wave shuffle then cross-wave via LDS ---
    #pragma unroll
    for (int off = 32; off > 0; off >>= 1) {
        lsum += __shfl_down(lsum, off, 64);
        ldup += __shfl_down(ldup, off, 64);
        loob |= __shfl_down(loob, off, 64);
    }
    const int wave = tid >> 6;
    if ((tid & 63) == 0) { s_sum[wave] = lsum; s_dup[wave] = ldup; s_oob[wave] = loob; }
    __syncthreads();
    if (tid == 0) {
        float bs = 0.0f; int bd = 0, bo = 0;
        #pragma unroll
        for (int w = 0; w < NWAVES; ++w) { bs += s_sum[w]; bd += s_dup[w]; bo |= s_oob[w]; }
        blk_sum[blockIdx.x] = bs;
        blk_dup[blockIdx.x] = bd;
        blk_oob[blockIdx.x] = bo;
    }
}

#define FBLOCK 256
#define FNWAVES (FBLOCK / 64)

__global__ __launch_bounds__(FBLOCK) void puzzle_final(
    const float* __restrict__ blk_sum, const int* __restrict__ blk_dup,
    const int* __restrict__ blk_oob, int nblocks,
    long long n_total, long long batch, float* __restrict__ out)
{
    __shared__ double s_sum[FNWAVES];
    __shared__ int    s_dup[FNWAVES];
    __shared__ int    s_oob[FNWAVES];

    double lsum = 0.0;
    int ldup = 0, loob = 0;
    for (int i = threadIdx.x; i < nblocks; i += FBLOCK) {
        lsum += (double)blk_sum[i];
        ldup += blk_dup[i];
        loob |= blk_oob[i];
    }
    #pragma unroll
    for (int off = 32; off > 0; off >>= 1) {
        lsum += __shfl_down(lsum, off, 64);
        ldup += __shfl_down(ldup, off, 64);
        loob |= __shfl_down(loob, off, 64);
    }
    const int wave = threadIdx.x >> 6;
    if ((threadIdx.x & 63) == 0) { s_sum[wave] = lsum; s_dup[wave] = ldup; s_oob[wave] = loob; }
    __syncthreads();
    if (threadIdx.x == 0) {
        double bs = 0.0; int bd = 0, bo = 0;
        #pragma unroll
        for (int w = 0; w < FNWAVES; ++w) { bs += s_sum[w]; bd += s_dup[w]; bo |= s_oob[w]; }
        const float loss1 = (float)(bs / (double)n_total);
        const float loss2 = (float)((double)bd * 0.1 / (double)batch);
        out[0] = loss1 + loss2 + (bo ? 1000.0f : 0.0f);
    }
}

extern "C" void kernel_launch(void* const* d_in, const int* in_sizes, int n_in,
                              void* d_out, int out_size, void* d_ws, size_t ws_size,
                              hipStream_t stream) {
    const float* preds = (const float*)d_in[0];
    const int*   tgts  = (const int*)d_in[1];
    float* out = (float*)d_out;

    const long long n = (long long)in_sizes[0];
    const long long batch = n / 25;
    const int nblocks = (int)((n + ELEMS_PER_BLOCK - 1) / ELEMS_PER_BLOCK);

    // workspace layout: [float sums | int dups | int oobs], each nblocks long
    float* blk_sum = (float*)d_ws;
    int*   blk_dup = (int*)(blk_sum + nblocks);
    int*   blk_oob = (int*)(blk_dup + nblocks);

    puzzle_main<<<nblocks, BLOCK, 0, stream>>>(preds, tgts, n,
                                               blk_sum, blk_dup, blk_oob);
    puzzle_final<<<1, FBLOCK, 0, stream>>>(blk_sum, blk_dup, blk_oob,
                                           nblocks, n, batch, out);
}